// Round 9
// baseline (36.012 us; speedup 1.0000x reference)
//
#include <hip/hip_runtime.h>
#include <hip/hip_bf16.h>

typedef __bf16 bf16x8 __attribute__((ext_vector_type(8)));
typedef float f32x4 __attribute__((ext_vector_type(4)));

#define G 8
#define B 32
#define D 32
#define O 32
#define K 4096   // N*T (floats per W row)
#define T 64
#define KSPLIT 2
#define KCHUNK (K / KSPLIT)   // 2048 floats
#define BK 256                // floats staged per row per step (1KB burst)
#define NSTEP (KCHUNK / BK)   // 8
#define MROWS 16              // o-rows per block

// ws: XB bf16 [K/32][B][32] = 256 KB only.
#define XB_ELEMS (B * K)

// Fused prep: threads [0,16384) build XB (MFMA B-frag order, no mask);
// threads [16384, 49152) init out[b][d][o] = bias[d][o] (gemm atomically adds).
__global__ __launch_bounds__(256) void prep_and_init(const float* __restrict__ x,
                                                     const float* __restrict__ bias,
                                                     __bf16* __restrict__ xb,
                                                     float* __restrict__ out) {
    int tid = blockIdx.x * 256 + threadIdx.x;
    if (tid < 16384) {
        int b = (tid >> 2) & 31;
        int k = (tid >> 7) * 32 + (tid & 3) * 8;
        const float4 x0 = *(const float4*)(x + b * K + k);
        const float4 x1 = *(const float4*)(x + b * K + k + 4);
        bf16x8 r;
        r[0] = (__bf16)x0.x; r[1] = (__bf16)x0.y; r[2] = (__bf16)x0.z; r[3] = (__bf16)x0.w;
        r[4] = (__bf16)x1.x; r[5] = (__bf16)x1.y; r[6] = (__bf16)x1.z; r[7] = (__bf16)x1.w;
        *(bf16x8*)(xb + (size_t)tid * 8) = r;   // flat idx == tid*8: coalesced
    } else {
        int t2 = tid - 16384;           // 32768 = B*D*O, out flat = b*1024 + d*32 + o
        out[t2] = bias[t2 & 1023];
    }
}

// Block (d, g, oh, ks): M = 16 contiguous o-rows, N = 32 b, K-half ks.
// 128 threads = 2 waves; wave bh covers b in [16*bh, 16*bh+16).
// W staged via global_load_lds, 1KB contiguous burst per o-row per step;
// XOR chunk-swizzle (row&7)<<4 on source AND lds-read addrs (rule 21).
// mask[o][t] applied to the A-fragment before bf16 convert.
// 32KB LDS/block -> 4 independent blocks/CU.
//
// Pipeline (the R8 fix): per step, xb fragment loads (XLOAD, 8 global->reg)
// are issued OLDER than STAGE(next) (8 global_load_lds). s_waitcnt vmcnt(8)
// then retires exactly {XLOAD(cur), STAGE(cur)} while STAGE(next)'s 8 loads
// remain in flight across BOTH barriers and the whole compute phase (T4:
// never drain to 0 mid-loop). Raw s_barriers; order pinned by sched_barrier.
__global__ __launch_bounds__(128) void gemm_main(const float* __restrict__ W,
                                                 const __bf16* __restrict__ xb,
                                                 const float* __restrict__ mask,
                                                 const float* __restrict__ y,
                                                 float* __restrict__ out) {
    __shared__ float ldsW[2][MROWS * BK];   // 2 x 16 KB
    const int d = blockIdx.x, g = blockIdx.y;
    const int oh = blockIdx.z & 1, ks = blockIdx.z >> 1;
    const int wid  = threadIdx.x >> 6;      // 0..1 = bh
    const int lane = threadIdx.x & 63;
    const int bh = wid;
    const int l15 = lane & 15, g16 = lane >> 4;

    // A-fragment: local row = l15, within-row byte = s*128 + g16*32 (+16 hi), swizzled
    const int lds_ro = l15 * 1024 + ((g16 * 32) ^ ((l15 & 7) * 16));

    // mask row o = oh*16 + l15; lane needs t = (s&1)*32 + g16*8 + j
    const float* mrow = mask + (oh * 16 + l15) * T + g16 * 8;
    const float4 me0 = *(const float4*)(mrow);
    const float4 me1 = *(const float4*)(mrow + 4);
    const float4 mo0 = *(const float4*)(mrow + 32);
    const float4 mo1 = *(const float4*)(mrow + 36);

    // XB: k-tile kt = ks*64 + step*8 + s; elem = kt*1024 + b*32 + g16*8
    const __bf16* xbl = xb + (size_t)(ks * (KCHUNK / 32)) * 1024
                           + (bh * 16 + l15) * 32 + g16 * 8;

    // staging: wave wid stages local rows 8*wid .. 8*wid+7
    const size_t wrow0 = ((size_t)(g * D + d) * O + oh * 16 + 8 * wid) * K
                         + (size_t)ks * KCHUNK;

    f32x4 acc = {0.f, 0.f, 0.f, 0.f};

#define STAGE(buf, step)                                                          \
    {                                                                             \
        _Pragma("unroll")                                                         \
        for (int i = 0; i < 8; ++i) {                                             \
            const int row = 8 * wid + i;                                          \
            const char* src = (const char*)(W + wrow0 + (size_t)i * K             \
                                            + (size_t)(step) * BK)                \
                              + ((lane * 16) ^ (i * 16));                         \
            __builtin_amdgcn_global_load_lds(                                     \
                (const __attribute__((address_space(1))) void*)src,               \
                (__attribute__((address_space(3))) void*)((char*)&ldsW[buf][0]    \
                                                          + row * 1024),          \
                16, 0, 0);                                                        \
        }                                                                         \
    }

    bf16x8 xr[8];
#define XLOAD(step)                                                               \
    {                                                                             \
        _Pragma("unroll")                                                         \
        for (int s = 0; s < 8; ++s)                                               \
            xr[s] = *(const bf16x8*)(xbl + (size_t)(step) * 8192                  \
                                         + (size_t)s * 1024);                     \
    }

    STAGE(0, 0);

    #pragma unroll
    for (int step = 0; step < NSTEP; ++step) {
        const int cur = step & 1;

        XLOAD(step);                         // 8 loads, older than next stage
        __builtin_amdgcn_sched_barrier(0);
        if (step + 1 < NSTEP) {
            STAGE(cur ^ 1, step + 1);        // 8 loads, stay in flight all step
            __builtin_amdgcn_sched_barrier(0);
            asm volatile("s_waitcnt vmcnt(8)" ::: "memory");  // XLOAD+STAGE(cur) done
        } else {
            __builtin_amdgcn_sched_barrier(0);
            asm volatile("s_waitcnt vmcnt(0)" ::: "memory");
        }
        __builtin_amdgcn_s_barrier();        // raw: no drain of prefetch
        __builtin_amdgcn_sched_barrier(0);

        const char* lb = (const char*)&ldsW[cur][0];
        #pragma unroll
        for (int s = 0; s < 8; ++s) {
            const int a0 = lds_ro + s * 128;
            const f32x4 alo = *(const f32x4*)(lb + a0);
            const f32x4 ahi = *(const f32x4*)(lb + (a0 ^ 16));
            const float4 ms0 = (s & 1) ? mo0 : me0;
            const float4 ms1 = (s & 1) ? mo1 : me1;
            bf16x8 af;
            af[0] = (__bf16)(alo[0] * ms0.x); af[1] = (__bf16)(alo[1] * ms0.y);
            af[2] = (__bf16)(alo[2] * ms0.z); af[3] = (__bf16)(alo[3] * ms0.w);
            af[4] = (__bf16)(ahi[0] * ms1.x); af[5] = (__bf16)(ahi[1] * ms1.y);
            af[6] = (__bf16)(ahi[2] * ms1.z); af[7] = (__bf16)(ahi[3] * ms1.w);
            acc = __builtin_amdgcn_mfma_f32_16x16x32_bf16(af, xr[s], acc, 0, 0, 0);
        }

        __builtin_amdgcn_sched_barrier(0);
        asm volatile("s_waitcnt lgkmcnt(0)" ::: "memory");  // ds_reads of cur done
        __builtin_amdgcn_s_barrier();        // safe to overwrite cur next iter
    }
#undef STAGE
#undef XLOAD

    // C/D: lane holds D[row=g16*4+i][col=l15]; row = o-in-tile, col = b-in-tile
    const int bg = bh * 16 + l15;                 // global b
    const float yv = y[bg * G + g];
    float* op = out + bg * (D * O) + d * O + oh * 16;
    #pragma unroll
    for (int i = 0; i < 4; ++i)
        unsafeAtomicAdd(op + g16 * 4 + i, yv * acc[i]);
}

extern "C" void kernel_launch(void* const* d_in, const int* in_sizes, int n_in,
                              void* d_out, int out_size, void* d_ws, size_t ws_size,
                              hipStream_t stream) {
    const float* x    = (const float*)d_in[0];
    const float* y    = (const float*)d_in[1];
    const float* w    = (const float*)d_in[2];
    const float* bias = (const float*)d_in[3];
    const float* mask = (const float*)d_in[4];
    float* out = (float*)d_out;

    __bf16* xbp = (__bf16*)d_ws;

    prep_and_init<<<192, 256, 0, stream>>>(x, bias, xbp, out);
    gemm_main<<<dim3(D, G, 4), 128, 0, stream>>>(w, xbp, mask, y, out);
}